// Round 1
// baseline (296.645 us; speedup 1.0000x reference)
//
#include <hip/hip_runtime.h>

#define BINS  30
#define NROWS 8192
#define NCOLS 2048

// ws layout:
//   [0, 245760)        : unsigned int counts[BINS][NCOLS]
//   [245760, 491520)   : float invw[BINS][NCOLS]   (precomputed per-(bin,col) weight)
//   [491520, 491528)   : double accum
#define WS_COUNTS_OFF 0
#define WS_INVW_OFF   (BINS * NCOLS * 4)
#define WS_ACCUM_OFF  (2 * BINS * NCOLS * 4)

// ---------------------------------------------------------------------------
// Kernel 1: per-column histogram of bin indices.
// Grid (NCOLS/64, 16), block 256. Each block: 64 cols x 512 rows.
// Lane i of each wave -> column i  => coalesced 256B/wave loads and
// LDS bank = col%32 => 2-way aliasing only (free), no intra-instr contention.
// ---------------------------------------------------------------------------
__global__ __launch_bounds__(256) void k_hist(
    const float* __restrict__ preds, const int* __restrict__ targets,
    unsigned int* __restrict__ counts)
{
    __shared__ unsigned int hist[BINS * 64];
    const int tid = threadIdx.x;
    for (int i = tid; i < BINS * 64; i += 256) hist[i] = 0u;
    __syncthreads();

    const int colBase = blockIdx.x * 64;
    const int rowBase = blockIdx.y * (NROWS / 16);     // 512 rows per block
    const int col     = tid & 63;
    const int rowOff  = tid >> 6;                      // 0..3

    const size_t cidx = (size_t)colBase + col;
    #pragma unroll 4
    for (int r = rowBase + rowOff; r < rowBase + NROWS / 16; r += 4) {
        const size_t idx = (size_t)r * NCOLS + cidx;
        float p = preds[idx];
        float t = (float)targets[idx];
        float s = 1.0f / (1.0f + expf(-p));
        float g = fabsf(s - t);
        int   b = (int)(g * 30.0f);                    // g >= 0 so trunc == floor
        b = b > (BINS - 1) ? (BINS - 1) : b;
        atomicAdd(&hist[b * 64 + col], 1u);
    }
    __syncthreads();

    for (int i = tid; i < BINS * 64; i += 256) {
        unsigned int v = hist[i];
        if (v) atomicAdd(&counts[(size_t)(i >> 6) * NCOLS + colBase + (i & 63)], v);
    }
}

// ---------------------------------------------------------------------------
// Kernel 2: EMA + weight table.
// invw[b][c] = (N / (0.75*acc_sum + 0.25*counts)) / max(n[c],1)
// One thread per column; 8 blocks x 256.
// ---------------------------------------------------------------------------
__global__ __launch_bounds__(256) void k_weights(
    const unsigned int* __restrict__ counts, const float* __restrict__ acc_sum,
    float* __restrict__ invw)
{
    const int c = blockIdx.x * 256 + threadIdx.x;
    float acc[BINS];
    int n = 0;
    #pragma unroll
    for (int b = 0; b < BINS; ++b) {
        unsigned int cnt = counts[(size_t)b * NCOLS + c];
        n += (cnt >= 1u) ? 1 : 0;
        acc[b] = 0.75f * acc_sum[(size_t)b * NCOLS + c] + 0.25f * (float)cnt;
    }
    const float rn = 1.0f / (float)(n > 1 ? n : 1);
    #pragma unroll
    for (int b = 0; b < BINS; ++b) {
        invw[(size_t)b * NCOLS + c] = ((float)NROWS / acc[b]) * rn;
    }
}

// ---------------------------------------------------------------------------
// Kernel 3: weighted BCE reduction.
// Grid (NCOLS/256, 64), block 256. Each block: 256 cols x 128 rows.
// Weight tile staged in LDS: addr = b*256 + tid => bank = tid%32, 2-way free.
// Bin computation is bit-identical to k_hist (self-consistent gather).
// ---------------------------------------------------------------------------
__global__ __launch_bounds__(256) void k_loss(
    const float* __restrict__ preds, const int* __restrict__ targets,
    const float* __restrict__ invw, double* __restrict__ accum)
{
    __shared__ float w_lds[BINS * 256];
    __shared__ float wave_sums[4];
    const int tid     = threadIdx.x;
    const int colBase = blockIdx.x * 256;
    const int rowBase = blockIdx.y * (NROWS / 64);     // 128 rows per block

    #pragma unroll
    for (int b = 0; b < BINS; ++b)
        w_lds[b * 256 + tid] = invw[(size_t)b * NCOLS + colBase + tid];
    __syncthreads();

    float sum = 0.0f;
    #pragma unroll 4
    for (int r = rowBase; r < rowBase + NROWS / 64; ++r) {
        const size_t idx = (size_t)r * NCOLS + colBase + tid;
        float p = preds[idx];
        float t = (float)targets[idx];
        float s = 1.0f / (1.0f + expf(-p));
        float g = fabsf(s - t);
        int   b = (int)(g * 30.0f);
        b = b > (BINS - 1) ? (BINS - 1) : b;
        float w   = w_lds[b * 256 + tid];
        // stable logaddexp(0,p) - p*t
        float bce = fmaxf(p, 0.0f) + log1pf(expf(-fabsf(p))) - p * t;
        sum += w * bce;
    }

    // wave (64-lane) reduce, then cross-wave via LDS
    #pragma unroll
    for (int off = 32; off > 0; off >>= 1)
        sum += __shfl_down(sum, off, 64);
    if ((tid & 63) == 0) wave_sums[tid >> 6] = sum;
    __syncthreads();
    if (tid == 0) {
        float s4 = wave_sums[0] + wave_sums[1] + wave_sums[2] + wave_sums[3];
        atomicAdd(accum, (double)s4);
    }
}

// ---------------------------------------------------------------------------
// Kernel 4: finalize mean.
// ---------------------------------------------------------------------------
__global__ void k_final(const double* __restrict__ accum, float* __restrict__ out)
{
    out[0] = (float)(accum[0] * (1.0 / ((double)NROWS * (double)NCOLS)));
}

extern "C" void kernel_launch(void* const* d_in, const int* in_sizes, int n_in,
                              void* d_out, int out_size, void* d_ws, size_t ws_size,
                              hipStream_t stream)
{
    const float* preds   = (const float*)d_in[0];
    const int*   targets = (const int*)d_in[1];
    const float* acc_sum = (const float*)d_in[2];

    unsigned int* counts = (unsigned int*)((char*)d_ws + WS_COUNTS_OFF);
    float*        invw   = (float*)((char*)d_ws + WS_INVW_OFF);
    double*       accum  = (double*)((char*)d_ws + WS_ACCUM_OFF);

    // zero counts + accum (invw is fully overwritten by k_weights)
    hipMemsetAsync(d_ws, 0, WS_ACCUM_OFF + 8, stream);

    dim3 g1(NCOLS / 64, 16);      // 512 blocks
    k_hist<<<g1, 256, 0, stream>>>(preds, targets, counts);

    k_weights<<<NCOLS / 256, 256, 0, stream>>>(counts, acc_sum, invw);

    dim3 g3(NCOLS / 256, 64);     // 512 blocks
    k_loss<<<g3, 256, 0, stream>>>(preds, targets, invw, accum);

    k_final<<<1, 1, 0, stream>>>(accum, (float*)d_out);
}

// Round 2
// 228.840 us; speedup vs baseline: 1.2963x; 1.2963x over previous
//
#include <hip/hip_runtime.h>

#define BINS  30
#define NROWS 8192
#define NCOLS 2048

// ws layout:
//   [0, 245760)        : unsigned int counts[BINS][NCOLS]
//   [245760, 491520)   : float bceSum[BINS][NCOLS]
//   [491520, 491528)   : double accum (loss numerator, pre-scaled)
#define WS_COUNTS_OFF 0
#define WS_S_OFF      (BINS * NCOLS * 4)
#define WS_ACCUM_OFF  (2 * BINS * NCOLS * 4)

// ---------------------------------------------------------------------------
// Kernel 1: single pass over preds/targets.
// Accumulates per-(bin,col) element COUNT and BCE SUM in LDS, flushes to
// global via atomics. Grid (32, 16) x 1024 threads: block = 64 cols x 512
// rows, 2 blocks/CU -> 32 waves/CU (full occupancy).
// LDS addr = b*64 + col, col = lane&63 -> bank = col%32, 2-way only (free).
// ---------------------------------------------------------------------------
__global__ __launch_bounds__(1024) void k_main(
    const float* __restrict__ preds, const int* __restrict__ targets,
    unsigned int* __restrict__ counts, float* __restrict__ bceSum)
{
    __shared__ unsigned int h_cnt[BINS * 64];
    __shared__ float        h_sum[BINS * 64];
    const int tid = threadIdx.x;
    for (int i = tid; i < BINS * 64; i += 1024) { h_cnt[i] = 0u; h_sum[i] = 0.0f; }
    __syncthreads();

    const int colBase = blockIdx.x * 64;
    const int col     = tid & 63;
    const int rowOff  = tid >> 6;                       // 0..15
    const int rowBase = blockIdx.y * (NROWS / 16);      // 512 rows per block

    const size_t cidx = (size_t)colBase + col;
    #pragma unroll 4
    for (int r = rowBase + rowOff; r < rowBase + NROWS / 16; r += 16) {
        const size_t idx = (size_t)r * NCOLS + cidx;
        float p  = preds[idx];
        float t  = (float)targets[idx];
        float ap = fabsf(p);
        float e  = __expf(-ap);                         // exp(-|p|), one v_exp
        float r1 = __builtin_amdgcn_rcpf(1.0f + e);     // 1/(1+e)
        // sigmoid(p): p>=0 -> r1 ; p<0 -> e*r1
        float sig = (p >= 0.0f) ? r1 : e * r1;
        float g   = fabsf(sig - t);
        int   b   = (int)(g * 30.0f);
        b = b > (BINS - 1) ? (BINS - 1) : b;
        // stable bce = max(p,0) + log(1+exp(-|p|)) - p*t
        float bce = fmaxf(p, 0.0f) + __logf(1.0f + e) - p * t;
        atomicAdd(&h_cnt[b * 64 + col], 1u);
        atomicAdd(&h_sum[b * 64 + col], bce);
    }
    __syncthreads();

    for (int i = tid; i < BINS * 64; i += 1024) {
        unsigned int v = h_cnt[i];
        const size_t gidx = (size_t)(i >> 6) * NCOLS + colBase + (i & 63);
        if (v) {
            atomicAdd(&counts[gidx], v);
            atomicAdd(&bceSum[gidx], h_sum[i]);
        }
    }
}

// ---------------------------------------------------------------------------
// Kernel 2: contract the 30x2048 table.
// loss = sum_{b,c} S[b,c] / (acc_new[b,c] * max(n_c,1) * NCOLS)
// where acc_new = 0.75*acc_sum + 0.25*counts, n_c = #bins with counts>=1.
// One thread per column; 8 blocks x 256. One double atomic per block.
// ---------------------------------------------------------------------------
__global__ __launch_bounds__(256) void k_finalize(
    const unsigned int* __restrict__ counts, const float* __restrict__ bceSum,
    const float* __restrict__ acc_sum, double* __restrict__ accum)
{
    __shared__ float wave_sums[4];
    const int tid = threadIdx.x;
    const int c   = blockIdx.x * 256 + tid;

    float colsum = 0.0f;
    int n = 0;
    #pragma unroll
    for (int b = 0; b < BINS; ++b) {
        const size_t gidx = (size_t)b * NCOLS + c;
        unsigned int cnt  = counts[gidx];
        if (cnt >= 1u) {
            n += 1;
            float acc_new = 0.75f * acc_sum[gidx] + 0.25f * (float)cnt;
            colsum += bceSum[gidx] / acc_new;   // acc_new >= 0.25 when cnt>0
        }
    }
    colsum /= (float)((n > 1 ? n : 1) * NCOLS);

    #pragma unroll
    for (int off = 32; off > 0; off >>= 1)
        colsum += __shfl_down(colsum, off, 64);
    if ((tid & 63) == 0) wave_sums[tid >> 6] = colsum;
    __syncthreads();
    if (tid == 0) {
        float s4 = wave_sums[0] + wave_sums[1] + wave_sums[2] + wave_sums[3];
        atomicAdd(accum, (double)s4);
    }
}

// ---------------------------------------------------------------------------
// Kernel 3: write scalar output. accum already includes all scaling; the
// reference divides the weighted sum by N elementwise via weights = N/acc,
// then means over N*C -> our accum = sum S/(acc*n*C); multiply by 1.0 = done?
// Reference: loss = (1/(N*C)) * sum (N/(acc*n)) * bce = sum bce/(acc*n*C).
// So accum IS the loss. LOSS_WEIGHT = 1.
// ---------------------------------------------------------------------------
__global__ void k_final(const double* __restrict__ accum, float* __restrict__ out)
{
    out[0] = (float)accum[0];
}

extern "C" void kernel_launch(void* const* d_in, const int* in_sizes, int n_in,
                              void* d_out, int out_size, void* d_ws, size_t ws_size,
                              hipStream_t stream)
{
    const float* preds   = (const float*)d_in[0];
    const int*   targets = (const int*)d_in[1];
    const float* acc_sum = (const float*)d_in[2];

    unsigned int* counts = (unsigned int*)((char*)d_ws + WS_COUNTS_OFF);
    float*        bceSum = (float*)((char*)d_ws + WS_S_OFF);
    double*       accum  = (double*)((char*)d_ws + WS_ACCUM_OFF);

    hipMemsetAsync(d_ws, 0, WS_ACCUM_OFF + 8, stream);

    dim3 g1(NCOLS / 64, 16);      // 512 blocks x 1024 threads
    k_main<<<g1, 1024, 0, stream>>>(preds, targets, counts, bceSum);

    k_finalize<<<NCOLS / 256, 256, 0, stream>>>(counts, bceSum, acc_sum, accum);

    k_final<<<1, 1, 0, stream>>>(accum, (float*)d_out);
}

// Round 3
// 227.928 us; speedup vs baseline: 1.3015x; 1.0040x over previous
//
#include <hip/hip_runtime.h>

#define BINS  30
#define NROWS 8192
#define NCOLS 2048
#define YSLICES 32
#define COLS_PER_BLK 128          // grid.x = 16
#define ROWS_PER_BLK (NROWS / YSLICES)   // 256

// ws layout (bytes), all plain-stored before read -> no zeroing needed:
//   part_cnt : float[YSLICES][BINS][NCOLS]   [0, 7864320)
//   part_sum : float[YSLICES][BINS][NCOLS]   [7864320, 15728640)
//   counts   : float[BINS][NCOLS]            [15728640, +245760)
//   bceSum   : float[BINS][NCOLS]            [15974400, +245760)
//   blockPart: float[8]                      [16220160, +32)
#define WS_PART_CNT 0
#define WS_PART_SUM (YSLICES * BINS * NCOLS * 4)
#define WS_COUNTS   (2 * YSLICES * BINS * NCOLS * 4)
#define WS_BCESUM   (WS_COUNTS + BINS * NCOLS * 4)
#define WS_BPART    (WS_BCESUM + BINS * NCOLS * 4)

// ---------------------------------------------------------------------------
// Kernel A: one pass over preds/targets with float4/int4 loads.
// Block = 128 cols x 256 rows, 1024 threads (16 waves), 2 blocks/CU (100% occ).
// Wave-iteration: half-wave lanes 0-31 -> row r cols 4*l..4*l+3 (512B seg),
// lanes 32-63 -> row r+1 same cols (512B seg).
// LDS hist swizzled: addr = b*128 + j*32 + (lane&31) -> bank = lane%32, free.
// Flush: plain stores of the block's private histogram slice (no atomics).
// ---------------------------------------------------------------------------
__global__ __launch_bounds__(1024) void k_main(
    const float* __restrict__ preds, const int* __restrict__ targets,
    float* __restrict__ part_cnt, float* __restrict__ part_sum)
{
    __shared__ unsigned int h_cnt[BINS * COLS_PER_BLK];
    __shared__ float        h_sum[BINS * COLS_PER_BLK];
    const int tid = threadIdx.x;
    for (int i = tid; i < BINS * COLS_PER_BLK; i += 1024) { h_cnt[i] = 0u; h_sum[i] = 0.0f; }
    __syncthreads();

    const int colBase = blockIdx.x * COLS_PER_BLK;
    const int rowBase = blockIdx.y * ROWS_PER_BLK;
    const int wave = tid >> 6;
    const int lane = tid & 63;
    const int hl   = lane & 31;       // half-lane: column group
    const int rp   = lane >> 5;       // row parity within wave

    const int col0 = colBase + 4 * hl;
    #pragma unroll
    for (int k = 0; k < ROWS_PER_BLK / 32; ++k) {           // 8 iterations
        const int r = rowBase + k * 32 + wave * 2 + rp;
        const size_t idx = (size_t)r * NCOLS + col0;
        const float4 p4 = *(const float4*)(preds + idx);
        const int4   t4 = *(const int4*)(targets + idx);
        const float pv[4] = {p4.x, p4.y, p4.z, p4.w};
        const int   tv[4] = {t4.x, t4.y, t4.z, t4.w};
        #pragma unroll
        for (int j = 0; j < 4; ++j) {
            float p  = pv[j];
            float t  = (float)tv[j];
            float e  = __expf(-fabsf(p));                   // exp(-|p|)
            float r1 = __builtin_amdgcn_rcpf(1.0f + e);
            float sig = (p >= 0.0f) ? r1 : e * r1;
            float g   = fabsf(sig - t);
            int   b   = (int)(g * 30.0f);
            b = b > (BINS - 1) ? (BINS - 1) : b;
            float bce = fmaxf(p, 0.0f) + __logf(1.0f + e) - p * t;
            const int s = b * COLS_PER_BLK + j * 32 + hl;   // swizzled, bank-free
            atomicAdd(&h_cnt[s], 1u);
            atomicAdd(&h_sum[s], bce);
        }
    }
    __syncthreads();

    // flush private slice: part[y][b][col] = hist (unswizzle col)
    const size_t outBase = (size_t)blockIdx.y * BINS * NCOLS;
    for (int i = tid; i < BINS * COLS_PER_BLK; i += 1024) {
        const int b = i >> 7;
        const int s = i & 127;
        const int col = colBase + ((s & 31) << 2) + (s >> 5);
        const size_t o = outBase + (size_t)b * NCOLS + col;
        part_cnt[o] = (float)h_cnt[i];
        part_sum[o] = h_sum[i];
    }
}

// ---------------------------------------------------------------------------
// Kernel B1: reduce the 32 y-slices -> counts[b][c], bceSum[b][c].
// 61,440 threads (240 blocks x 256), 64 coalesced loads each.
// ---------------------------------------------------------------------------
__global__ __launch_bounds__(256) void k_reduce(
    const float* __restrict__ part_cnt, const float* __restrict__ part_sum,
    float* __restrict__ counts, float* __restrict__ bceSum)
{
    const int id = blockIdx.x * 256 + threadIdx.x;   // 0 .. 61439
    float c = 0.0f, s = 0.0f;
    #pragma unroll 8
    for (int y = 0; y < YSLICES; ++y) {
        c += part_cnt[(size_t)y * BINS * NCOLS + id];
        s += part_sum[(size_t)y * BINS * NCOLS + id];
    }
    counts[id] = c;
    bceSum[id] = s;
}

// ---------------------------------------------------------------------------
// Kernel B2: per-column weight contraction.
// loss contribution of col c: (1/(n_c*NCOLS)) * sum_b S[b,c]/acc_new[b,c].
// 8 blocks x 256; block partial via shuffle+LDS, plain store (no atomics).
// ---------------------------------------------------------------------------
__global__ __launch_bounds__(256) void k_colsum(
    const float* __restrict__ counts, const float* __restrict__ bceSum,
    const float* __restrict__ acc_sum, float* __restrict__ blockPart)
{
    __shared__ float wave_sums[4];
    const int tid = threadIdx.x;
    const int c   = blockIdx.x * 256 + tid;

    float colsum = 0.0f;
    int n = 0;
    #pragma unroll
    for (int b = 0; b < BINS; ++b) {
        const size_t gidx = (size_t)b * NCOLS + c;
        float cnt = counts[gidx];
        if (cnt >= 1.0f) {
            n += 1;
            float acc_new = 0.75f * acc_sum[gidx] + 0.25f * cnt;
            colsum += bceSum[gidx] / acc_new;
        }
    }
    colsum *= __builtin_amdgcn_rcpf((float)(n > 1 ? n : 1)) * (1.0f / (float)NCOLS);

    #pragma unroll
    for (int off = 32; off > 0; off >>= 1)
        colsum += __shfl_down(colsum, off, 64);
    if ((tid & 63) == 0) wave_sums[tid >> 6] = colsum;
    __syncthreads();
    if (tid == 0)
        blockPart[blockIdx.x] = wave_sums[0] + wave_sums[1] + wave_sums[2] + wave_sums[3];
}

// ---------------------------------------------------------------------------
// Kernel C: final scalar.
// ---------------------------------------------------------------------------
__global__ void k_final(const float* __restrict__ blockPart, float* __restrict__ out)
{
    double s = 0.0;
    #pragma unroll
    for (int i = 0; i < 8; ++i) s += (double)blockPart[i];
    out[0] = (float)s;
}

extern "C" void kernel_launch(void* const* d_in, const int* in_sizes, int n_in,
                              void* d_out, int out_size, void* d_ws, size_t ws_size,
                              hipStream_t stream)
{
    const float* preds   = (const float*)d_in[0];
    const int*   targets = (const int*)d_in[1];
    const float* acc_sum = (const float*)d_in[2];

    float* part_cnt  = (float*)((char*)d_ws + WS_PART_CNT);
    float* part_sum  = (float*)((char*)d_ws + WS_PART_SUM);
    float* counts    = (float*)((char*)d_ws + WS_COUNTS);
    float* bceSum    = (float*)((char*)d_ws + WS_BCESUM);
    float* blockPart = (float*)((char*)d_ws + WS_BPART);

    dim3 gA(NCOLS / COLS_PER_BLK, YSLICES);   // (16, 32) = 512 blocks
    k_main<<<gA, 1024, 0, stream>>>(preds, targets, part_cnt, part_sum);

    k_reduce<<<(BINS * NCOLS) / 256, 256, 0, stream>>>(part_cnt, part_sum, counts, bceSum);

    k_colsum<<<NCOLS / 256, 256, 0, stream>>>(counts, bceSum, acc_sum, blockPart);

    k_final<<<1, 1, 0, stream>>>(blockPart, (float*)d_out);
}

// Round 4
// 226.538 us; speedup vs baseline: 1.3095x; 1.0061x over previous
//
#include <hip/hip_runtime.h>

#define BINS  30
#define NROWS 8192
#define NCOLS 2048
#define YSLICES 32
#define COLS_PER_BLK 128                 // grid.x = 16
#define ROWS_PER_BLK (NROWS / YSLICES)   // 256

// ws layout (bytes), all plain-stored before read -> no zeroing needed:
//   part_cnt : float[YSLICES][BINS][NCOLS]
//   part_sum : float[YSLICES][BINS][NCOLS]
//   counts   : float[BINS][NCOLS]
//   bceSum   : float[BINS][NCOLS]
//   blockPart: float[8]
#define WS_PART_CNT 0
#define WS_PART_SUM (YSLICES * BINS * NCOLS * 4)
#define WS_COUNTS   (2 * YSLICES * BINS * NCOLS * 4)
#define WS_BCESUM   (WS_COUNTS + BINS * NCOLS * 4)
#define WS_BPART    (WS_BCESUM + BINS * NCOLS * 4)

// ---------------------------------------------------------------------------
// Kernel A: one pass over preds/targets, float4/int4 loads, depth-2 software
// pipeline (next iteration's loads in flight while current computes).
// Block = 128 cols x 256 rows, 1024 threads, 2 blocks/CU.
// Math: p' = t ? -p : p. Then g = sigmoid(p') and bce = softplus(p') =
// max(p',0) + log(1 + exp(-|p'|)).  (t=0: g=sig(p), bce=sp(p); t=1:
// g=1-sig(p), bce=sp(p)-p. Matches reference.)
// LDS hist swizzled: addr = b*128 + j*32 + (lane&31) -> bank = lane%32 (free).
// ---------------------------------------------------------------------------
__global__ __launch_bounds__(1024, 8) void k_main(
    const float* __restrict__ preds, const int* __restrict__ targets,
    float* __restrict__ part_cnt, float* __restrict__ part_sum)
{
    __shared__ unsigned int h_cnt[BINS * COLS_PER_BLK];
    __shared__ float        h_sum[BINS * COLS_PER_BLK];
    const int tid = threadIdx.x;
    for (int i = tid; i < BINS * COLS_PER_BLK; i += 1024) { h_cnt[i] = 0u; h_sum[i] = 0.0f; }
    __syncthreads();

    const int colBase = blockIdx.x * COLS_PER_BLK;
    const int wave = tid >> 6;
    const int lane = tid & 63;
    const int hl   = lane & 31;     // column group within tile
    const int rp   = lane >> 5;     // row parity within wave
    const int r0   = blockIdx.y * ROWS_PER_BLK + wave * 2 + rp;  // +32 per iter
    const int col0 = colBase + 4 * hl;

    const float4* pPtr = (const float4*)(preds   + (size_t)r0 * NCOLS + col0);
    const int4*   tPtr = (const int4*)  (targets + (size_t)r0 * NCOLS + col0);
    const int strideV = 32 * NCOLS / 4;   // 16384 float4s per 32 rows

    float4 p_cur = *pPtr;
    int4   t_cur = *tPtr;

    #pragma unroll
    for (int k = 0; k < ROWS_PER_BLK / 32; ++k) {        // 8 iterations
        float4 p_nxt = p_cur;
        int4   t_nxt = t_cur;
        if (k < ROWS_PER_BLK / 32 - 1) {
            pPtr += strideV; tPtr += strideV;
            p_nxt = *pPtr;                                // in flight during compute
            t_nxt = *tPtr;
        }
        const float pv[4] = {p_cur.x, p_cur.y, p_cur.z, p_cur.w};
        const int   tv[4] = {t_cur.x, t_cur.y, t_cur.z, t_cur.w};
        #pragma unroll
        for (int j = 0; j < 4; ++j) {
            float p  = pv[j];
            float pp = tv[j] ? -p : p;                    // p'
            float e  = __expf(-fabsf(pp));                // exp(-|p'|)
            float d  = 1.0f + e;
            float r1 = __builtin_amdgcn_rcpf(d);
            float g  = (pp >= 0.0f) ? r1 : e * r1;        // sigmoid(p')
            int   b  = (int)(g * 30.0f);
            b = b > (BINS - 1) ? (BINS - 1) : b;
            float bce = fmaxf(pp, 0.0f) + __logf(d);      // softplus(p')
            const int s = b * COLS_PER_BLK + j * 32 + hl; // bank-free
            atomicAdd(&h_cnt[s], 1u);
            atomicAdd(&h_sum[s], bce);
        }
        p_cur = p_nxt;
        t_cur = t_nxt;
    }
    __syncthreads();

    // flush private slice: part[y][b][col] (unswizzle col)
    const size_t outBase = (size_t)blockIdx.y * BINS * NCOLS;
    for (int i = tid; i < BINS * COLS_PER_BLK; i += 1024) {
        const int b = i >> 7;
        const int s = i & 127;
        const int col = colBase + ((s & 31) << 2) + (s >> 5);
        const size_t o = outBase + (size_t)b * NCOLS + col;
        part_cnt[o] = (float)h_cnt[i];
        part_sum[o] = h_sum[i];
    }
}

// ---------------------------------------------------------------------------
// Kernel B1: reduce 32 y-slices -> counts[b][c], bceSum[b][c].
// 240 blocks x 256 threads, fully coalesced.
// ---------------------------------------------------------------------------
__global__ __launch_bounds__(256) void k_reduce(
    const float* __restrict__ part_cnt, const float* __restrict__ part_sum,
    float* __restrict__ counts, float* __restrict__ bceSum)
{
    const int id = blockIdx.x * 256 + threadIdx.x;   // 0 .. 61439
    float c = 0.0f, s = 0.0f;
    #pragma unroll 8
    for (int y = 0; y < YSLICES; ++y) {
        c += part_cnt[(size_t)y * BINS * NCOLS + id];
        s += part_sum[(size_t)y * BINS * NCOLS + id];
    }
    counts[id] = c;
    bceSum[id] = s;
}

// ---------------------------------------------------------------------------
// Kernel B2: per-column contraction.
// col c contributes (1/(n_c*NCOLS)) * sum_b S[b,c]/acc_new[b,c].
// ---------------------------------------------------------------------------
__global__ __launch_bounds__(256) void k_colsum(
    const float* __restrict__ counts, const float* __restrict__ bceSum,
    const float* __restrict__ acc_sum, float* __restrict__ blockPart)
{
    __shared__ float wave_sums[4];
    const int tid = threadIdx.x;
    const int c   = blockIdx.x * 256 + tid;

    float colsum = 0.0f;
    int n = 0;
    #pragma unroll
    for (int b = 0; b < BINS; ++b) {
        const size_t gidx = (size_t)b * NCOLS + c;
        float cnt = counts[gidx];
        if (cnt >= 1.0f) {
            n += 1;
            float acc_new = 0.75f * acc_sum[gidx] + 0.25f * cnt;
            colsum += bceSum[gidx] / acc_new;
        }
    }
    colsum /= (float)((n > 1 ? n : 1) * NCOLS);

    #pragma unroll
    for (int off = 32; off > 0; off >>= 1)
        colsum += __shfl_down(colsum, off, 64);
    if ((tid & 63) == 0) wave_sums[tid >> 6] = colsum;
    __syncthreads();
    if (tid == 0)
        blockPart[blockIdx.x] = wave_sums[0] + wave_sums[1] + wave_sums[2] + wave_sums[3];
}

__global__ void k_final(const float* __restrict__ blockPart, float* __restrict__ out)
{
    double s = 0.0;
    #pragma unroll
    for (int i = 0; i < 8; ++i) s += (double)blockPart[i];
    out[0] = (float)s;
}

extern "C" void kernel_launch(void* const* d_in, const int* in_sizes, int n_in,
                              void* d_out, int out_size, void* d_ws, size_t ws_size,
                              hipStream_t stream)
{
    const float* preds   = (const float*)d_in[0];
    const int*   targets = (const int*)d_in[1];
    const float* acc_sum = (const float*)d_in[2];

    float* part_cnt  = (float*)((char*)d_ws + WS_PART_CNT);
    float* part_sum  = (float*)((char*)d_ws + WS_PART_SUM);
    float* counts    = (float*)((char*)d_ws + WS_COUNTS);
    float* bceSum    = (float*)((char*)d_ws + WS_BCESUM);
    float* blockPart = (float*)((char*)d_ws + WS_BPART);

    dim3 gA(NCOLS / COLS_PER_BLK, YSLICES);   // (16, 32) = 512 blocks
    k_main<<<gA, 1024, 0, stream>>>(preds, targets, part_cnt, part_sum);

    k_reduce<<<(BINS * NCOLS) / 256, 256, 0, stream>>>(part_cnt, part_sum, counts, bceSum);

    k_colsum<<<NCOLS / 256, 256, 0, stream>>>(counts, bceSum, acc_sum, blockPart);

    k_final<<<1, 1, 0, stream>>>(blockPart, (float*)d_out);
}

// Round 5
// 181.440 us; speedup vs baseline: 1.6349x; 1.2486x over previous
//
#include <hip/hip_runtime.h>

#define BINS  30
#define NROWS 8192
#define NCOLS 2048
#define YSLICES 32
#define COLS_PER_BLK 128                 // grid.x = 16
#define ROWS_PER_BLK (NROWS / YSLICES)   // 256

#define FIXED_SCALE 1048576.0f           // 2^20 fixed point for bce
#define SUM_MASK    ((1ull << 54) - 1)

// ws layout (bytes), all plain-stored before read -> no zeroing needed:
//   part_cnt : float[YSLICES][BINS][NCOLS]
//   part_sum : float[YSLICES][BINS][NCOLS]
//   counts   : float[BINS][NCOLS]
//   bceSum   : float[BINS][NCOLS]
//   blockPart: float[8]
#define WS_PART_CNT 0
#define WS_PART_SUM (YSLICES * BINS * NCOLS * 4)
#define WS_COUNTS   (2 * YSLICES * BINS * NCOLS * 4)
#define WS_BCESUM   (WS_COUNTS + BINS * NCOLS * 4)
#define WS_BPART    (WS_BCESUM + BINS * NCOLS * 4)

// ---------------------------------------------------------------------------
// Kernel A: one pass over preds/targets.
// Per element, ONE native u64 LDS atomic: packed = (1<<54) | round(bce*2^20).
//   - count accumulates in bits [54:63]  (<=256 per cell per block)
//   - bce fixed-point sum in bits [0:53] (<=1.5e9 per cell, no carry-out)
// This avoids float-atomic CAS loops entirely and halves atomic issue count.
// Depth-2 prefetch with UNCONDITIONAL clamped-address loads (compiler cannot
// sink them behind a branch).
// Block = 128 cols x 256 rows, 1024 threads, 2 blocks/CU.
// Math: p' = t ? -p : p;  g = sigmoid(p');  bce = softplus(p').
// LDS addr = b*128 + j*32 + (lane&31): u64 banks -> 4-way worst (1.58x, ok).
// ---------------------------------------------------------------------------
__global__ __launch_bounds__(1024, 8) void k_main(
    const float* __restrict__ preds, const int* __restrict__ targets,
    float* __restrict__ part_cnt, float* __restrict__ part_sum)
{
    __shared__ unsigned long long h_pack[BINS * COLS_PER_BLK];
    const int tid = threadIdx.x;
    for (int i = tid; i < BINS * COLS_PER_BLK; i += 1024) h_pack[i] = 0ull;
    __syncthreads();

    const int colBase = blockIdx.x * COLS_PER_BLK;
    const int wave = tid >> 6;
    const int lane = tid & 63;
    const int hl   = lane & 31;     // column group within tile
    const int rp   = lane >> 5;     // row parity within wave
    const int r0   = blockIdx.y * ROWS_PER_BLK + wave * 2 + rp;  // +32 per iter
    const int col0 = colBase + 4 * hl;

    const int NIT = ROWS_PER_BLK / 32;            // 8
    size_t base = (size_t)r0 * NCOLS + col0;      // element offset

    float4 p_cur = *(const float4*)(preds + base);
    int4   t_cur = *(const int4*)(targets + base);

    #pragma unroll
    for (int k = 0; k < NIT; ++k) {
        // unconditional prefetch (clamped: last iter reloads same line, L1 hit)
        base += (k < NIT - 1) ? (size_t)(32 * NCOLS) : 0;
        float4 p_nxt = *(const float4*)(preds + base);
        int4   t_nxt = *(const int4*)(targets + base);

        const float pv[4] = {p_cur.x, p_cur.y, p_cur.z, p_cur.w};
        const int   tv[4] = {t_cur.x, t_cur.y, t_cur.z, t_cur.w};
        #pragma unroll
        for (int j = 0; j < 4; ++j) {
            float p  = pv[j];
            float pp = tv[j] ? -p : p;                    // p'
            float e  = __expf(-fabsf(pp));                // exp(-|p'|)
            float d  = 1.0f + e;
            float r1 = __builtin_amdgcn_rcpf(d);
            float g  = (pp >= 0.0f) ? r1 : e * r1;        // sigmoid(p')
            int   b  = (int)(g * 30.0f);
            b = b > (BINS - 1) ? (BINS - 1) : b;
            float bce = fmaxf(pp, 0.0f) + __logf(d);      // softplus(p')
            unsigned long long pk =
                (1ull << 54) | (unsigned long long)(unsigned)(bce * FIXED_SCALE + 0.5f);
            const int s = b * COLS_PER_BLK + j * 32 + hl;
            atomicAdd(&h_pack[s], pk);                    // ds_add_u64, no CAS
        }
        p_cur = p_nxt;
        t_cur = t_nxt;
    }
    __syncthreads();

    // flush decoded private slice: part[y][b][col] (unswizzle col)
    const size_t outBase = (size_t)blockIdx.y * BINS * NCOLS;
    for (int i = tid; i < BINS * COLS_PER_BLK; i += 1024) {
        const unsigned long long v = h_pack[i];
        const int b = i >> 7;
        const int s = i & 127;
        const int col = colBase + ((s & 31) << 2) + (s >> 5);
        const size_t o = outBase + (size_t)b * NCOLS + col;
        part_cnt[o] = (float)(unsigned)(v >> 54);
        part_sum[o] = (float)(v & SUM_MASK) * (1.0f / FIXED_SCALE);
    }
}

// ---------------------------------------------------------------------------
// Kernel B1: reduce 32 y-slices -> counts[b][c], bceSum[b][c].
// 240 blocks x 256 threads, fully coalesced.
// ---------------------------------------------------------------------------
__global__ __launch_bounds__(256) void k_reduce(
    const float* __restrict__ part_cnt, const float* __restrict__ part_sum,
    float* __restrict__ counts, float* __restrict__ bceSum)
{
    const int id = blockIdx.x * 256 + threadIdx.x;   // 0 .. 61439
    float c = 0.0f, s = 0.0f;
    #pragma unroll 8
    for (int y = 0; y < YSLICES; ++y) {
        c += part_cnt[(size_t)y * BINS * NCOLS + id];
        s += part_sum[(size_t)y * BINS * NCOLS + id];
    }
    counts[id] = c;
    bceSum[id] = s;
}

// ---------------------------------------------------------------------------
// Kernel B2: per-column contraction.
// col c contributes (1/(n_c*NCOLS)) * sum_b S[b,c]/acc_new[b,c].
// ---------------------------------------------------------------------------
__global__ __launch_bounds__(256) void k_colsum(
    const float* __restrict__ counts, const float* __restrict__ bceSum,
    const float* __restrict__ acc_sum, float* __restrict__ blockPart)
{
    __shared__ float wave_sums[4];
    const int tid = threadIdx.x;
    const int c   = blockIdx.x * 256 + tid;

    float colsum = 0.0f;
    int n = 0;
    #pragma unroll
    for (int b = 0; b < BINS; ++b) {
        const size_t gidx = (size_t)b * NCOLS + c;
        float cnt = counts[gidx];
        if (cnt >= 1.0f) {
            n += 1;
            float acc_new = 0.75f * acc_sum[gidx] + 0.25f * cnt;
            colsum += bceSum[gidx] / acc_new;
        }
    }
    colsum /= (float)((n > 1 ? n : 1) * NCOLS);

    #pragma unroll
    for (int off = 32; off > 0; off >>= 1)
        colsum += __shfl_down(colsum, off, 64);
    if ((tid & 63) == 0) wave_sums[tid >> 6] = colsum;
    __syncthreads();
    if (tid == 0)
        blockPart[blockIdx.x] = wave_sums[0] + wave_sums[1] + wave_sums[2] + wave_sums[3];
}

__global__ void k_final(const float* __restrict__ blockPart, float* __restrict__ out)
{
    double s = 0.0;
    #pragma unroll
    for (int i = 0; i < 8; ++i) s += (double)blockPart[i];
    out[0] = (float)s;
}

extern "C" void kernel_launch(void* const* d_in, const int* in_sizes, int n_in,
                              void* d_out, int out_size, void* d_ws, size_t ws_size,
                              hipStream_t stream)
{
    const float* preds   = (const float*)d_in[0];
    const int*   targets = (const int*)d_in[1];
    const float* acc_sum = (const float*)d_in[2];

    float* part_cnt  = (float*)((char*)d_ws + WS_PART_CNT);
    float* part_sum  = (float*)((char*)d_ws + WS_PART_SUM);
    float* counts    = (float*)((char*)d_ws + WS_COUNTS);
    float* bceSum    = (float*)((char*)d_ws + WS_BCESUM);
    float* blockPart = (float*)((char*)d_ws + WS_BPART);

    dim3 gA(NCOLS / COLS_PER_BLK, YSLICES);   // (16, 32) = 512 blocks
    k_main<<<gA, 1024, 0, stream>>>(preds, targets, part_cnt, part_sum);

    k_reduce<<<(BINS * NCOLS) / 256, 256, 0, stream>>>(part_cnt, part_sum, counts, bceSum);

    k_colsum<<<NCOLS / 256, 256, 0, stream>>>(counts, bceSum, acc_sum, blockPart);

    k_final<<<1, 1, 0, stream>>>(blockPart, (float*)d_out);
}